// Round 3
// baseline (450.050 us; speedup 1.0000x reference)
//
#include <hip/hip_runtime.h>
#include <hip/hip_bf16.h>
#include <stdint.h>

#define T_SEQ 4096
#define DIMX 1024
#define NH 16
#define HD 64
#define DLAT 256

typedef __bf16 bf16x8 __attribute__((ext_vector_type(8)));
typedef float floatx4 __attribute__((ext_vector_type(4)));

#define MFMA(a, b, c) __builtin_amdgcn_mfma_f32_16x16x32_bf16(a, b, c, 0, 0, 0)

// ---------- dtype detect: f32 buffer -> flag=1, packed-bf16 -> flag=0 -------
__global__ __launch_bounds__(256) void detect_kernel(const uint32_t* __restrict__ xbits,
                                                     int* __restrict__ flag) {
  __shared__ int cnt;
  if (threadIdx.x == 0) cnt = 0;
  __syncthreads();
  int ok = 0;
  for (int i = threadIdx.x; i < 4096; i += 256) {
    uint32_t u = xbits[i];
    uint32_t e = (u >> 23) & 0xFF;
    if (e >= 97 && e <= 137) ok++;  // f32 ~N(0,1) exponent band
  }
  atomicAdd(&cnt, ok);
  __syncthreads();
  if (threadIdx.x == 0) *flag = (cnt > 2048) ? 1 : 0;
}

// ---------- convert x to bf16 (vectorized, dtype-aware) ---------------------
__global__ __launch_bounds__(256) void cvt_kernel(const void* __restrict__ in,
                                                  __bf16* __restrict__ out,
                                                  const int* __restrict__ flag,
                                                  int n8) {
  int i = blockIdx.x * 256 + threadIdx.x;
  if (i >= n8) return;
  if (*flag) {
    const float4* p = (const float4*)in;
    float4 a = p[2 * i], b = p[2 * i + 1];
    bf16x8 r = {(__bf16)a.x, (__bf16)a.y, (__bf16)a.z, (__bf16)a.w,
                (__bf16)b.x, (__bf16)b.y, (__bf16)b.z, (__bf16)b.w};
    *(bf16x8*)(out + 8 * (size_t)i) = r;
  } else {
    *(bf16x8*)(out + 8 * (size_t)i) = ((const bf16x8*)in)[i];
  }
}

// ---------- transpose: in (R x C) -> out (C x R), dims % 64 == 0, dtype-aware
__global__ __launch_bounds__(256) void tr_kernel(const void* __restrict__ in,
                                                 __bf16* __restrict__ out,
                                                 const int* __restrict__ flag,
                                                 int R, int C) {
  __shared__ __bf16 t[64][65];
  int r0 = blockIdx.y * 64, c0 = blockIdx.x * 64;
  int tid = threadIdx.x;
  bool isf = (*flag != 0);
#pragma unroll
  for (int i = 0; i < 16; i++) {
    int idx = tid + i * 256;
    int r = idx >> 6, c = idx & 63;
    size_t gi = (size_t)(r0 + r) * C + c0 + c;
    t[r][c] = isf ? (__bf16)((const float*)in)[gi] : ((const __bf16*)in)[gi];
  }
  __syncthreads();
#pragma unroll
  for (int i = 0; i < 16; i++) {
    int idx = tid + i * 256;
    int rr = idx & 63, cc = idx >> 6;
    out[(size_t)(c0 + cc) * R + r0 + rr] = t[rr][cc];
  }
}

// ---------- bf16->bf16 transpose (for V -> V^T) -----------------------------
__global__ __launch_bounds__(256) void tr_bf_kernel(const __bf16* __restrict__ in,
                                                    __bf16* __restrict__ out,
                                                    int R, int C) {
  __shared__ __bf16 t[64][65];
  int r0 = blockIdx.y * 64, c0 = blockIdx.x * 64;
  int tid = threadIdx.x;
#pragma unroll
  for (int i = 0; i < 16; i++) {
    int idx = tid + i * 256;
    int r = idx >> 6, c = idx & 63;
    t[r][c] = in[(size_t)(r0 + r) * C + c0 + c];
  }
  __syncthreads();
#pragma unroll
  for (int i = 0; i < 16; i++) {
    int idx = tid + i * 256;
    int rr = idx & 63, cc = idx >> 6;
    out[(size_t)(c0 + cc) * R + r0 + rr] = t[rr][cc];
  }
}

// ---------- GEMM: C(MxN) = A(MxK) * Bt(NxK)^T, bf16 in, OUT_T out ----------
#define ASTR 56
template <typename OUT_T>
__global__ __launch_bounds__(256) void gemm_bt(const __bf16* __restrict__ A,
                                               const __bf16* __restrict__ Bt,
                                               OUT_T* __restrict__ C,
                                               int M, int N, int K) {
  __shared__ __attribute__((aligned(16))) __bf16 Al[64 * ASTR];
  __shared__ __attribute__((aligned(16))) __bf16 Bl[64 * ASTR];
  int tid = threadIdx.x;
  int wave = tid >> 6, lane = tid & 63;
  int quad = lane >> 4, l16 = lane & 15;
  int n0 = blockIdx.x * 64, m0 = blockIdx.y * 64;
  int srow = tid >> 2, skc = (tid & 3) << 3;

  floatx4 acc[4];
#pragma unroll
  for (int i = 0; i < 4; i++) acc[i] = (floatx4){0.f, 0.f, 0.f, 0.f};

  const __bf16* Ap = A + (size_t)(m0 + srow) * K + skc;
  const __bf16* Bp = Bt + (size_t)(n0 + srow) * K + skc;

  for (int k0 = 0; k0 < K; k0 += 32) {
    *(bf16x8*)&Al[srow * ASTR + skc] = *(const bf16x8*)(Ap + k0);
    *(bf16x8*)&Bl[srow * ASTR + skc] = *(const bf16x8*)(Bp + k0);
    __syncthreads();
    bf16x8 af = *(const bf16x8*)&Al[(wave * 16 + l16) * ASTR + quad * 8];
#pragma unroll
    for (int nt = 0; nt < 4; nt++) {
      bf16x8 bfr = *(const bf16x8*)&Bl[(nt * 16 + l16) * ASTR + quad * 8];
      acc[nt] = MFMA(af, bfr, acc[nt]);
    }
    __syncthreads();
  }
#pragma unroll
  for (int nt = 0; nt < 4; nt++)
#pragma unroll
    for (int r = 0; r < 4; r++) {
      int row = m0 + wave * 16 + quad * 4 + r;
      int col = n0 + nt * 16 + l16;
      C[(size_t)row * N + col] = (OUT_T)acc[nt][r];
    }
}

// ---------- flash attention, causal, one block = (head, 64 q rows) ----------
#define AST 88
__global__ __launch_bounds__(256) void mla_attn(const __bf16* __restrict__ Q,
                                                const __bf16* __restrict__ Kg,
                                                const __bf16* __restrict__ Vt,
                                                __bf16* __restrict__ ctx) {
  __shared__ __attribute__((aligned(16))) __bf16 Kl[64 * AST];
  __shared__ __attribute__((aligned(16))) __bf16 Vl[64 * AST];
  __shared__ __attribute__((aligned(16))) __bf16 Pl[64 * AST];
  int tid = threadIdx.x;
  int wave = tid >> 6, lane = tid & 63;
  int quad = lane >> 4, l16 = lane & 15;
  int qt = blockIdx.x, h = blockIdx.y;
  int q0 = qt * 64;
  int srow = tid >> 3, skc = (tid & 7) << 3;

#pragma unroll
  for (int i = 0; i < 2; i++) {
    int r = srow + i * 32;
    *(bf16x8*)&Pl[r * AST + skc] =
        *(const bf16x8*)&Q[(size_t)(q0 + r) * DIMX + h * HD + skc];
  }
  __syncthreads();
  bf16x8 qf0 = *(const bf16x8*)&Pl[(wave * 16 + l16) * AST + quad * 8];
  bf16x8 qf1 = *(const bf16x8*)&Pl[(wave * 16 + l16) * AST + 32 + quad * 8];
  __syncthreads();

  floatx4 o[4];
#pragma unroll
  for (int i = 0; i < 4; i++) o[i] = (floatx4){0.f, 0.f, 0.f, 0.f};
  float m_i[4], l_i[4];
#pragma unroll
  for (int r = 0; r < 4; r++) { m_i[r] = -1e30f; l_i[r] = 0.f; }

  for (int kt = 0; kt <= qt; kt++) {
    int k0 = kt * 64;
#pragma unroll
    for (int i = 0; i < 2; i++) {
      int r = srow + i * 32;
      *(bf16x8*)&Kl[r * AST + skc] =
          *(const bf16x8*)&Kg[(size_t)(k0 + r) * DIMX + h * HD + skc];
      *(bf16x8*)&Vl[r * AST + skc] =
          *(const bf16x8*)&Vt[(size_t)(h * HD + r) * T_SEQ + k0 + skc];
    }
    __syncthreads();

    floatx4 s[4];
#pragma unroll
    for (int ct = 0; ct < 4; ct++) {
      bf16x8 kf0 = *(const bf16x8*)&Kl[(ct * 16 + l16) * AST + quad * 8];
      bf16x8 kf1 = *(const bf16x8*)&Kl[(ct * 16 + l16) * AST + 32 + quad * 8];
      floatx4 z = (floatx4){0.f, 0.f, 0.f, 0.f};
      z = MFMA(qf0, kf0, z);
      z = MFMA(qf1, kf1, z);
      s[ct] = z;
    }
#pragma unroll
    for (int ct = 0; ct < 4; ct++)
#pragma unroll
      for (int r = 0; r < 4; r++) {
        float v = s[ct][r] * 0.125f;
        if (kt == qt) {
          int grow = wave * 16 + quad * 4 + r;
          int gcol = ct * 16 + l16;
          if (gcol > grow) v = -1e30f;
        }
        s[ct][r] = v;
      }
    float mx[4];
#pragma unroll
    for (int r = 0; r < 4; r++)
      mx[r] = fmaxf(fmaxf(s[0][r], s[1][r]), fmaxf(s[2][r], s[3][r]));
#pragma unroll
    for (int off = 1; off < 16; off <<= 1)
#pragma unroll
      for (int r = 0; r < 4; r++)
        mx[r] = fmaxf(mx[r], __shfl_xor(mx[r], off, 64));
    float alpha[4], rs[4];
#pragma unroll
    for (int r = 0; r < 4; r++) {
      float mn = fmaxf(m_i[r], mx[r]);
      alpha[r] = __expf(m_i[r] - mn);
      m_i[r] = mn;
      rs[r] = 0.f;
    }
#pragma unroll
    for (int ct = 0; ct < 4; ct++)
#pragma unroll
      for (int r = 0; r < 4; r++) {
        float p = __expf(s[ct][r] - m_i[r]);
        s[ct][r] = p;
        rs[r] += p;
      }
#pragma unroll
    for (int off = 1; off < 16; off <<= 1)
#pragma unroll
      for (int r = 0; r < 4; r++) rs[r] += __shfl_xor(rs[r], off, 64);
#pragma unroll
    for (int r = 0; r < 4; r++) l_i[r] = l_i[r] * alpha[r] + rs[r];
#pragma unroll
    for (int dt = 0; dt < 4; dt++)
#pragma unroll
      for (int r = 0; r < 4; r++) o[dt][r] *= alpha[r];

#pragma unroll
    for (int ct = 0; ct < 4; ct++)
#pragma unroll
      for (int r = 0; r < 4; r++)
        Pl[(wave * 16 + quad * 4 + r) * AST + ct * 16 + l16] = (__bf16)s[ct][r];
    __syncthreads();
    bf16x8 pf0 = *(const bf16x8*)&Pl[(wave * 16 + l16) * AST + quad * 8];
    bf16x8 pf1 = *(const bf16x8*)&Pl[(wave * 16 + l16) * AST + 32 + quad * 8];
#pragma unroll
    for (int dt = 0; dt < 4; dt++) {
      bf16x8 vf0 = *(const bf16x8*)&Vl[(dt * 16 + l16) * AST + quad * 8];
      bf16x8 vf1 = *(const bf16x8*)&Vl[(dt * 16 + l16) * AST + 32 + quad * 8];
      o[dt] = MFMA(pf0, vf0, o[dt]);
      o[dt] = MFMA(pf1, vf1, o[dt]);
    }
    __syncthreads();
  }
#pragma unroll
  for (int dt = 0; dt < 4; dt++)
#pragma unroll
    for (int r = 0; r < 4; r++) {
      float val = o[dt][r] / l_i[r];
      int row = q0 + wave * 16 + quad * 4 + r;
      int col = h * HD + dt * 16 + l16;
      ctx[(size_t)row * DIMX + col] = (__bf16)val;
    }
}

extern "C" void kernel_launch(void* const* d_in, const int* in_sizes, int n_in,
                              void* d_out, int out_size, void* d_ws,
                              size_t ws_size, hipStream_t stream) {
  const void* x_raw = d_in[0];
  const void* wdkv = d_in[1];
  const void* wuk = d_in[2];
  const void* wuv = d_in[3];
  const void* wuq = d_in[4];
  const void* wo = d_in[5];
  float* out = (float*)d_out;  // reference output dtype is float32

  char* base = (char*)d_ws;
  int* flag = (int*)base;
  __bf16* ws = (__bf16*)(base + 256);
  __bf16* x_bf = ws;                               // T*D
  __bf16* q = x_bf + (size_t)T_SEQ * DIMX;         // T*D
  __bf16* k = q + (size_t)T_SEQ * DIMX;            // T*D
  __bf16* v = k + (size_t)T_SEQ * DIMX;            // T*D
  __bf16* vt = v + (size_t)T_SEQ * DIMX;           // D*T
  __bf16* ctx = vt + (size_t)T_SEQ * DIMX;         // T*D
  __bf16* ckv = ctx + (size_t)T_SEQ * DIMX;        // T*DLAT
  __bf16* wt_dkv = ckv + (size_t)T_SEQ * DLAT;     // DLAT x DIM
  __bf16* wt_uk = wt_dkv + (size_t)DLAT * DIMX;    // DIM x DLAT
  __bf16* wt_uv = wt_uk + (size_t)DIMX * DLAT;     // DIM x DLAT
  __bf16* wt_uq = wt_uv + (size_t)DIMX * DLAT;     // DIM x DIM
  __bf16* wt_o = wt_uq + (size_t)DIMX * DIMX;      // DIM x DIM

  dim3 blk(256);
  detect_kernel<<<1, blk, 0, stream>>>((const uint32_t*)x_raw, flag);
  cvt_kernel<<<dim3(T_SEQ * DIMX / 8 / 256), blk, 0, stream>>>(x_raw, x_bf, flag,
                                                               T_SEQ * DIMX / 8);
  // weight transposes (B^T form for gemm_bt), dtype-aware
  tr_kernel<<<dim3(DLAT / 64, DIMX / 64), blk, 0, stream>>>(wdkv, wt_dkv, flag, DIMX, DLAT);
  tr_kernel<<<dim3(DIMX / 64, DLAT / 64), blk, 0, stream>>>(wuk, wt_uk, flag, DLAT, DIMX);
  tr_kernel<<<dim3(DIMX / 64, DLAT / 64), blk, 0, stream>>>(wuv, wt_uv, flag, DLAT, DIMX);
  tr_kernel<<<dim3(DIMX / 64, DIMX / 64), blk, 0, stream>>>(wuq, wt_uq, flag, DIMX, DIMX);
  tr_kernel<<<dim3(DIMX / 64, DIMX / 64), blk, 0, stream>>>(wo, wt_o, flag, DIMX, DIMX);
  // projections (bf16 intermediates)
  gemm_bt<__bf16><<<dim3(DLAT / 64, T_SEQ / 64), blk, 0, stream>>>(x_bf, wt_dkv, ckv, T_SEQ, DLAT, DIMX);
  gemm_bt<__bf16><<<dim3(DIMX / 64, T_SEQ / 64), blk, 0, stream>>>(x_bf, wt_uq, q, T_SEQ, DIMX, DIMX);
  gemm_bt<__bf16><<<dim3(DIMX / 64, T_SEQ / 64), blk, 0, stream>>>(ckv, wt_uk, k, T_SEQ, DIMX, DLAT);
  gemm_bt<__bf16><<<dim3(DIMX / 64, T_SEQ / 64), blk, 0, stream>>>(ckv, wt_uv, v, T_SEQ, DIMX, DLAT);
  // V -> V^T (rows: d = h*64+hd, cols: t)
  tr_bf_kernel<<<dim3(DIMX / 64, T_SEQ / 64), blk, 0, stream>>>(v, vt, T_SEQ, DIMX);
  // attention
  mla_attn<<<dim3(T_SEQ / 64, NH), blk, 0, stream>>>(q, k, vt, ctx);
  // output projection -> float32 d_out
  gemm_bt<float><<<dim3(DIMX / 64, T_SEQ / 64), blk, 0, stream>>>(ctx, wt_o, out, T_SEQ, DIMX, DIMX);
}

// Round 4
// 315.045 us; speedup vs baseline: 1.4285x; 1.4285x over previous
//
#include <hip/hip_runtime.h>
#include <hip/hip_bf16.h>
#include <stdint.h>

#define T_SEQ 4096
#define DIMX 1024
#define NH 16
#define HD 64
#define DLAT 256

typedef __bf16 bf16x8 __attribute__((ext_vector_type(8)));
typedef float floatx4 __attribute__((ext_vector_type(4)));

#define MFMA(a, b, c) __builtin_amdgcn_mfma_f32_16x16x32_bf16(a, b, c, 0, 0, 0)

// ---------- prep: x f32->bf16 convert + 5 weight transposes, one launch -----
// blocks [0,2048): cvt x (4096*1024 elems, 8/thread)
// blocks [2048,...): 64x64 transpose tiles of the 5 weights (f32 in, bf16^T out)
__global__ __launch_bounds__(256) void prep_kernel(
    const float* __restrict__ x, const float* __restrict__ wdkv,
    const float* __restrict__ wuk, const float* __restrict__ wuv,
    const float* __restrict__ wuq, const float* __restrict__ wo,
    __bf16* __restrict__ x_bf, __bf16* __restrict__ wt_dkv,
    __bf16* __restrict__ wt_uk, __bf16* __restrict__ wt_uv,
    __bf16* __restrict__ wt_uq, __bf16* __restrict__ wt_o) {
  int id = blockIdx.x;
  if (id < 2048) {
    int i = id * 256 + threadIdx.x;
    const float4* p = (const float4*)x;
    float4 a = p[2 * i], b = p[2 * i + 1];
    bf16x8 r = {(__bf16)a.x, (__bf16)a.y, (__bf16)a.z, (__bf16)a.w,
                (__bf16)b.x, (__bf16)b.y, (__bf16)b.z, (__bf16)b.w};
    *(bf16x8*)(x_bf + 8 * (size_t)i) = r;
    return;
  }
  int t = id - 2048;
  const float* in;
  __bf16* out;
  int R, C, lt;
  if (t < 64)       { in = wdkv; out = wt_dkv; R = 1024; C = 256;  lt = t; }
  else if (t < 128) { in = wuk;  out = wt_uk;  R = 256;  C = 1024; lt = t - 64; }
  else if (t < 192) { in = wuv;  out = wt_uv;  R = 256;  C = 1024; lt = t - 128; }
  else if (t < 448) { in = wuq;  out = wt_uq;  R = 1024; C = 1024; lt = t - 192; }
  else              { in = wo;   out = wt_o;   R = 1024; C = 1024; lt = t - 448; }
  __shared__ __bf16 tls[64][65];
  int tpr = C >> 6;
  int r0 = (lt / tpr) * 64, c0 = (lt % tpr) * 64;
  int tid = threadIdx.x;
#pragma unroll
  for (int i = 0; i < 16; i++) {
    int idx = tid + i * 256;
    int r = idx >> 6, c = idx & 63;
    tls[r][c] = (__bf16)in[(size_t)(r0 + r) * C + c0 + c];
  }
  __syncthreads();
#pragma unroll
  for (int i = 0; i < 16; i++) {
    int idx = tid + i * 256;
    int rr = idx & 63, cc = idx >> 6;
    out[(size_t)(c0 + cc) * R + r0 + rr] = tls[rr][cc];
  }
}

// ---------- bf16->bf16 transpose (V -> V^T) ---------------------------------
__global__ __launch_bounds__(256) void tr_bf_kernel(const __bf16* __restrict__ in,
                                                    __bf16* __restrict__ out,
                                                    int R, int C) {
  __shared__ __bf16 t[64][65];
  int r0 = blockIdx.y * 64, c0 = blockIdx.x * 64;
  int tid = threadIdx.x;
#pragma unroll
  for (int i = 0; i < 16; i++) {
    int idx = tid + i * 256;
    int r = idx >> 6, c = idx & 63;
    t[r][c] = in[(size_t)(r0 + r) * C + c0 + c];
  }
  __syncthreads();
#pragma unroll
  for (int i = 0; i < 16; i++) {
    int idx = tid + i * 256;
    int rr = idx & 63, cc = idx >> 6;
    out[(size_t)(c0 + cc) * R + r0 + rr] = t[rr][cc];
  }
}

// ---------- GEMM: C(MxN) = A(MxK) * Bt(NxK)^T, bf16 in, OUT_T out -----------
#define ASTR 56
template <typename OUT_T>
__global__ __launch_bounds__(256) void gemm_bt(const __bf16* __restrict__ A,
                                               const __bf16* __restrict__ Bt,
                                               OUT_T* __restrict__ C,
                                               int M, int N, int K) {
  __shared__ __attribute__((aligned(16))) __bf16 Al[64 * ASTR];
  __shared__ __attribute__((aligned(16))) __bf16 Bl[64 * ASTR];
  int tid = threadIdx.x;
  int wave = tid >> 6, lane = tid & 63;
  int quad = lane >> 4, l16 = lane & 15;
  int n0 = blockIdx.x * 64, m0 = blockIdx.y * 64;
  int srow = tid >> 2, skc = (tid & 3) << 3;

  floatx4 acc[4];
#pragma unroll
  for (int i = 0; i < 4; i++) acc[i] = (floatx4){0.f, 0.f, 0.f, 0.f};

  const __bf16* Ap = A + (size_t)(m0 + srow) * K + skc;
  const __bf16* Bp = Bt + (size_t)(n0 + srow) * K + skc;

  for (int k0 = 0; k0 < K; k0 += 32) {
    *(bf16x8*)&Al[srow * ASTR + skc] = *(const bf16x8*)(Ap + k0);
    *(bf16x8*)&Bl[srow * ASTR + skc] = *(const bf16x8*)(Bp + k0);
    __syncthreads();
    bf16x8 af = *(const bf16x8*)&Al[(wave * 16 + l16) * ASTR + quad * 8];
#pragma unroll
    for (int nt = 0; nt < 4; nt++) {
      bf16x8 bfr = *(const bf16x8*)&Bl[(nt * 16 + l16) * ASTR + quad * 8];
      acc[nt] = MFMA(af, bfr, acc[nt]);
    }
    __syncthreads();
  }
#pragma unroll
  for (int nt = 0; nt < 4; nt++)
#pragma unroll
    for (int r = 0; r < 4; r++) {
      int row = m0 + wave * 16 + quad * 4 + r;
      int col = n0 + nt * 16 + l16;
      C[(size_t)row * N + col] = (OUT_T)acc[nt][r];
    }
}

// ---------- flash attention, causal, paired q-tiles (qa, 63-qa) -------------
// Shared k-loop: kt = 0..qb; strip-a updates gated by block-uniform kt<=qa.
// Every block does exactly 65 MFMA tile-units -> balanced critical path.
#define AST 88
__global__ __launch_bounds__(256) void mla_attn2(const __bf16* __restrict__ Q,
                                                 const __bf16* __restrict__ Kg,
                                                 const __bf16* __restrict__ Vt,
                                                 __bf16* __restrict__ ctx) {
  __shared__ __attribute__((aligned(16))) __bf16 Kl[64 * AST];
  __shared__ __attribute__((aligned(16))) __bf16 Vl[64 * AST];
  __shared__ __attribute__((aligned(16))) __bf16 Pa[64 * AST];
  __shared__ __attribute__((aligned(16))) __bf16 Pb[64 * AST];
  int tid = threadIdx.x;
  int wave = tid >> 6, lane = tid & 63;
  int quad = lane >> 4, l16 = lane & 15;
  int qa = blockIdx.x, h = blockIdx.y;
  int qb = 63 - qa;
  int a0 = qa * 64, b0 = qb * 64;
  int srow = tid >> 3, skc = (tid & 7) << 3;

  // stage both Q tiles, pull A-frags into registers
#pragma unroll
  for (int i = 0; i < 2; i++) {
    int r = srow + i * 32;
    *(bf16x8*)&Pa[r * AST + skc] =
        *(const bf16x8*)&Q[(size_t)(a0 + r) * DIMX + h * HD + skc];
    *(bf16x8*)&Pb[r * AST + skc] =
        *(const bf16x8*)&Q[(size_t)(b0 + r) * DIMX + h * HD + skc];
  }
  __syncthreads();
  int fr = (wave * 16 + l16) * AST + quad * 8;
  bf16x8 qfa0 = *(const bf16x8*)&Pa[fr];
  bf16x8 qfa1 = *(const bf16x8*)&Pa[fr + 32];
  bf16x8 qfb0 = *(const bf16x8*)&Pb[fr];
  bf16x8 qfb1 = *(const bf16x8*)&Pb[fr + 32];
  // safe: first in-loop __syncthreads precedes any Pa/Pb overwrite

  floatx4 oa[4], ob[4];
  float ma[4], la[4], mb[4], lb[4];
#pragma unroll
  for (int i = 0; i < 4; i++) {
    oa[i] = (floatx4){0.f, 0.f, 0.f, 0.f};
    ob[i] = (floatx4){0.f, 0.f, 0.f, 0.f};
    ma[i] = -1e30f; la[i] = 0.f; mb[i] = -1e30f; lb[i] = 0.f;
  }

  // strip step: S = q K^T (from Kl), mask, online softmax, write P to Pl
  auto strip = [&](bf16x8 f0, bf16x8 f1, float* m_i, float* l_i, floatx4* o,
                   __bf16* Pl, bool diag) {
    floatx4 s[4];
#pragma unroll
    for (int ct = 0; ct < 4; ct++) {
      bf16x8 kf0 = *(const bf16x8*)&Kl[(ct * 16 + l16) * AST + quad * 8];
      bf16x8 kf1 = *(const bf16x8*)&Kl[(ct * 16 + l16) * AST + 32 + quad * 8];
      floatx4 z = (floatx4){0.f, 0.f, 0.f, 0.f};
      z = MFMA(f0, kf0, z);
      z = MFMA(f1, kf1, z);
      s[ct] = z;
    }
#pragma unroll
    for (int ct = 0; ct < 4; ct++)
#pragma unroll
      for (int r = 0; r < 4; r++) {
        float v = s[ct][r] * 0.125f;
        if (diag) {
          int grow = wave * 16 + quad * 4 + r;
          int gcol = ct * 16 + l16;
          if (gcol > grow) v = -1e30f;
        }
        s[ct][r] = v;
      }
    float mx[4];
#pragma unroll
    for (int r = 0; r < 4; r++)
      mx[r] = fmaxf(fmaxf(s[0][r], s[1][r]), fmaxf(s[2][r], s[3][r]));
#pragma unroll
    for (int off = 1; off < 16; off <<= 1)
#pragma unroll
      for (int r = 0; r < 4; r++)
        mx[r] = fmaxf(mx[r], __shfl_xor(mx[r], off, 64));
    float alpha[4], rs[4];
#pragma unroll
    for (int r = 0; r < 4; r++) {
      float mn = fmaxf(m_i[r], mx[r]);
      alpha[r] = __expf(m_i[r] - mn);
      m_i[r] = mn;
      rs[r] = 0.f;
    }
#pragma unroll
    for (int ct = 0; ct < 4; ct++)
#pragma unroll
      for (int r = 0; r < 4; r++) {
        float p = __expf(s[ct][r] - m_i[r]);
        s[ct][r] = p;
        rs[r] += p;
      }
#pragma unroll
    for (int off = 1; off < 16; off <<= 1)
#pragma unroll
      for (int r = 0; r < 4; r++) rs[r] += __shfl_xor(rs[r], off, 64);
#pragma unroll
    for (int r = 0; r < 4; r++) l_i[r] = l_i[r] * alpha[r] + rs[r];
#pragma unroll
    for (int dt = 0; dt < 4; dt++)
#pragma unroll
      for (int r = 0; r < 4; r++) o[dt][r] *= alpha[r];
#pragma unroll
    for (int ct = 0; ct < 4; ct++)
#pragma unroll
      for (int r = 0; r < 4; r++)
        Pl[(wave * 16 + quad * 4 + r) * AST + ct * 16 + l16] = (__bf16)s[ct][r];
  };

  auto pv = [&](floatx4* o, const __bf16* Pl) {
    bf16x8 pf0 = *(const bf16x8*)&Pl[fr];
    bf16x8 pf1 = *(const bf16x8*)&Pl[fr + 32];
#pragma unroll
    for (int dt = 0; dt < 4; dt++) {
      bf16x8 vf0 = *(const bf16x8*)&Vl[(dt * 16 + l16) * AST + quad * 8];
      bf16x8 vf1 = *(const bf16x8*)&Vl[(dt * 16 + l16) * AST + 32 + quad * 8];
      o[dt] = MFMA(pf0, vf0, o[dt]);
      o[dt] = MFMA(pf1, vf1, o[dt]);
    }
  };

  for (int kt = 0; kt <= qb; kt++) {
    int k0 = kt * 64;
#pragma unroll
    for (int i = 0; i < 2; i++) {
      int r = srow + i * 32;
      *(bf16x8*)&Kl[r * AST + skc] =
          *(const bf16x8*)&Kg[(size_t)(k0 + r) * DIMX + h * HD + skc];
      *(bf16x8*)&Vl[r * AST + skc] =
          *(const bf16x8*)&Vt[(size_t)(h * HD + r) * T_SEQ + k0 + skc];
    }
    __syncthreads();
    bool doA = (kt <= qa);
    strip(qfb0, qfb1, mb, lb, ob, Pb, kt == qb);
    if (doA) strip(qfa0, qfa1, ma, la, oa, Pa, kt == qa);
    __syncthreads();
    pv(ob, Pb);
    if (doA) pv(oa, Pa);
    __syncthreads();
  }

  auto store = [&](floatx4* o, float* l_i, int base) {
#pragma unroll
    for (int dt = 0; dt < 4; dt++)
#pragma unroll
      for (int r = 0; r < 4; r++) {
        float val = o[dt][r] / l_i[r];
        int row = base + wave * 16 + quad * 4 + r;
        int col = h * HD + dt * 16 + l16;
        ctx[(size_t)row * DIMX + col] = (__bf16)val;
      }
  };
  store(oa, la, a0);
  store(ob, lb, b0);
}

extern "C" void kernel_launch(void* const* d_in, const int* in_sizes, int n_in,
                              void* d_out, int out_size, void* d_ws,
                              size_t ws_size, hipStream_t stream) {
  const float* x = (const float*)d_in[0];
  const float* wdkv = (const float*)d_in[1];
  const float* wuk = (const float*)d_in[2];
  const float* wuv = (const float*)d_in[3];
  const float* wuq = (const float*)d_in[4];
  const float* wo = (const float*)d_in[5];
  float* out = (float*)d_out;  // reference output dtype is float32

  __bf16* ws = (__bf16*)d_ws;
  __bf16* x_bf = ws;                               // T*D
  __bf16* q = x_bf + (size_t)T_SEQ * DIMX;         // T*D
  __bf16* k = q + (size_t)T_SEQ * DIMX;            // T*D
  __bf16* v = k + (size_t)T_SEQ * DIMX;            // T*D
  __bf16* vt = v + (size_t)T_SEQ * DIMX;           // D*T
  __bf16* ctx = vt + (size_t)T_SEQ * DIMX;         // T*D
  __bf16* ckv = ctx + (size_t)T_SEQ * DIMX;        // T*DLAT
  __bf16* wt_dkv = ckv + (size_t)T_SEQ * DLAT;     // DLAT x DIM
  __bf16* wt_uk = wt_dkv + (size_t)DLAT * DIMX;    // DIM x DLAT
  __bf16* wt_uv = wt_uk + (size_t)DIMX * DLAT;     // DIM x DLAT
  __bf16* wt_uq = wt_uv + (size_t)DIMX * DLAT;     // DIM x DIM
  __bf16* wt_o = wt_uq + (size_t)DIMX * DIMX;      // DIM x DIM

  dim3 blk(256);
  prep_kernel<<<dim3(2752), blk, 0, stream>>>(x, wdkv, wuk, wuv, wuq, wo, x_bf,
                                              wt_dkv, wt_uk, wt_uv, wt_uq, wt_o);
  gemm_bt<__bf16><<<dim3(DLAT / 64, T_SEQ / 64), blk, 0, stream>>>(x_bf, wt_dkv, ckv, T_SEQ, DLAT, DIMX);
  gemm_bt<__bf16><<<dim3(DIMX / 64, T_SEQ / 64), blk, 0, stream>>>(x_bf, wt_uq, q, T_SEQ, DIMX, DIMX);
  gemm_bt<__bf16><<<dim3(DIMX / 64, T_SEQ / 64), blk, 0, stream>>>(ckv, wt_uk, k, T_SEQ, DIMX, DLAT);
  gemm_bt<__bf16><<<dim3(DIMX / 64, T_SEQ / 64), blk, 0, stream>>>(ckv, wt_uv, v, T_SEQ, DIMX, DLAT);
  tr_bf_kernel<<<dim3(DIMX / 64, T_SEQ / 64), blk, 0, stream>>>(v, vt, T_SEQ, DIMX);
  mla_attn2<<<dim3(32, NH), blk, 0, stream>>>(q, k, vt, ctx);
  gemm_bt<float><<<dim3(DIMX / 64, T_SEQ / 64), blk, 0, stream>>>(ctx, wt_o, out, T_SEQ, DIMX, DIMX);
}